// Round 1
// baseline (250.026 us; speedup 1.0000x reference)
//
#include <hip/hip_runtime.h>

// Problem shape (fixed by reference): N=8192 rows, D=512, user in [0,256).
// out[i,:] = (1/(m_i + 1e-16)) * sum_{j in S_i} emb[j,:]
// S_i = { j : is_click[j] && user[j]==user[i] && ts[j] < ts[i] }

constexpr int BLOCK = 256;

// ---------------------------------------------------------------------------
// is_click layout detection: jax bool may arrive as 1-byte bool or as int32.
// If int32: within the first n bytes, every byte at offset %4 != 0 is 0
// (values are 0/1 little-endian). If 1-byte bool with ~half ones, offsets
// %4!=0 will certainly contain nonzero bytes. Degenerate all-false input
// gives identical (all-zero) output under either interpretation.
// flag=1 -> bytewise (bool8), flag=0 -> int32.
__global__ void uht_detect_bool_layout(const unsigned char* __restrict__ clicks,
                                       int n, int* __restrict__ flag) {
    __shared__ int any;
    if (threadIdx.x == 0) any = 0;
    __syncthreads();
    int local = 0;
    for (int idx = threadIdx.x; idx < n; idx += blockDim.x) {
        if ((idx & 3) != 0 && clicks[idx] != 0) local = 1;
    }
    if (local) atomicOr(&any, 1);
    __syncthreads();
    if (threadIdx.x == 0) flag[0] = any;
}

// ---------------------------------------------------------------------------
// One block per output row i. Deterministic: match list is built with a
// prefix-scan (no atomics), accumulation order is fixed.
template <int N_ROWS, int D_DIM>
__global__ __launch_bounds__(BLOCK)
void uht_history_kernel(const int* __restrict__ user,
                        const float* __restrict__ ts,
                        const unsigned char* __restrict__ click_u8,
                        const float* __restrict__ emb,
                        float* __restrict__ out,
                        const int* __restrict__ layout_flag) {
    constexpr int CHUNK = N_ROWS / BLOCK;  // 32 j's per thread
    const int i = blockIdx.x;
    const int t = threadIdx.x;

    const int ui = user[i];
    const float ti = ts[i];
    const bool bytewise = (layout_flag[0] != 0);
    const int* click_i32 = (const int*)click_u8;

    __shared__ unsigned short list[N_ROWS];  // matched j indices (16 KB)
    __shared__ int sc[BLOCK];                // scan workspace

    // ---- phase 1: each thread scans contiguous chunk [t*CHUNK, (t+1)*CHUNK)
    const int j0 = t * CHUNK;
    unsigned int mb = 0;  // per-thread match bitmask (CHUNK<=32)
    int cnt = 0;
    #pragma unroll 4
    for (int k = 0; k < CHUNK; ++k) {
        const int j = j0 + k;
        const bool clicked = bytewise ? (click_u8[j] != 0) : (click_i32[j] != 0);
        const bool m = clicked && (user[j] == ui) && (ti > ts[j]);
        cnt += m ? 1 : 0;
        mb |= (m ? 1u : 0u) << k;
    }

    // ---- block-wide inclusive scan of counts (Hillis-Steele)
    sc[t] = cnt;
    __syncthreads();
    for (int d = 1; d < BLOCK; d <<= 1) {
        int v = (t >= d) ? sc[t - d] : 0;
        __syncthreads();
        sc[t] += v;
        __syncthreads();
    }
    const int total = sc[BLOCK - 1];
    int pos = sc[t] - cnt;  // exclusive offset

    // ---- write match list in deterministic (ascending-j) order
    for (int k = 0; k < CHUNK; ++k) {
        if (mb & (1u << k)) list[pos++] = (unsigned short)(j0 + k);
    }
    __syncthreads();

    // ---- phase 2: cooperative sum of matched embedding rows.
    // Thread t owns columns [2t, 2t+1] as a float2 (coalesced).
    const float2* __restrict__ emb2 = (const float2*)emb;
    float2 acc = make_float2(0.f, 0.f);
    for (int k = 0; k < total; ++k) {
        const int j = (int)list[k];  // LDS broadcast read
        const float2 e = emb2[(size_t)j * (D_DIM / 2) + t];
        acc.x += e.x;
        acc.y += e.y;
    }

    const float inv = 1.0f / ((float)total + 1e-16f);
    float2* out2 = (float2*)out;
    out2[(size_t)i * (D_DIM / 2) + t] = make_float2(acc.x * inv, acc.y * inv);
}

// ---------------------------------------------------------------------------
extern "C" void kernel_launch(void* const* d_in, const int* in_sizes, int n_in,
                              void* d_out, int out_size, void* d_ws, size_t ws_size,
                              hipStream_t stream) {
    const int* user = (const int*)d_in[0];
    const float* ts = (const float*)d_in[1];
    const unsigned char* clicks = (const unsigned char*)d_in[2];
    const float* emb = (const float*)d_in[3];
    float* out = (float*)d_out;
    int* flag = (int*)d_ws;

    const int n = in_sizes[0];  // 8192
    (void)n_in; (void)out_size; (void)ws_size;

    uht_detect_bool_layout<<<1, BLOCK, 0, stream>>>(clicks, n, flag);
    uht_history_kernel<8192, 512><<<8192, BLOCK, 0, stream>>>(
        user, ts, clicks, emb, out, flag);
}

// Round 2
// 36.205 us; speedup vs baseline: 6.9058x; 6.9058x over previous
//
#include <hip/hip_runtime.h>

// out[i,:] = (1/(m_i + 1e-16)) * sum_{j} emb[j,:]  over
// S_i = { j : is_click[j] && user[j]==user[i] && ts[j] < ts[i] }
// N=8192, D=512, user in [0,256).
//
// Strategy: one block per USER. Within a user group, sort members by
// (ts, j) -- a deterministic total order -- then walk in ascending ts
// maintaining a running sum S of clicked embeddings (distributed: thread t
// owns columns [2t,2t+1]). out[row] = S * 1/(c+eps) where c = #clicked
// strictly earlier. Tie-runs (equal ts) are flushed together so strict '<'
// semantics hold exactly.

constexpr int BLOCK   = 256;
constexpr int N_USERS = 256;
constexpr int CAP     = 1024;  // >> max group size (~64 for this data)

// ---------------------------------------------------------------------------
// is_click layout detection (jax bool as 1-byte vs int32). flag=1 -> bytewise.
__global__ void uht_detect_bool_layout(const unsigned char* __restrict__ clicks,
                                       int n, int* __restrict__ flag) {
    __shared__ int any;
    if (threadIdx.x == 0) any = 0;
    __syncthreads();
    int local = 0;
    for (int idx = threadIdx.x; idx < n; idx += blockDim.x) {
        if ((idx & 3) != 0 && clicks[idx] != 0) local = 1;
    }
    if (local) atomicOr(&any, 1);
    __syncthreads();
    if (threadIdx.x == 0) flag[0] = any;
}

// ---------------------------------------------------------------------------
template <int N_ROWS, int D_DIM>
__global__ __launch_bounds__(BLOCK)
void uht_user_walk_kernel(const int* __restrict__ user,
                          const float* __restrict__ ts,
                          const unsigned char* __restrict__ click_u8,
                          const float* __restrict__ emb,
                          float* __restrict__ out,
                          const int* __restrict__ layout_flag) {
    const int u = blockIdx.x;   // user id
    const int t = threadIdx.x;
    const bool bytewise = (layout_flag[0] != 0);
    const int* click_i32 = (const int*)click_u8;

    __shared__ int   mj[CAP];    // member row index (unordered)
    __shared__ float mts[CAP];
    __shared__ int   mclk[CAP];
    __shared__ int   sj[CAP];    // sorted by (ts, j)
    __shared__ float sts[CAP];
    __shared__ int   sclk[CAP];
    __shared__ int   cnt_lds;

    if (t == 0) cnt_lds = 0;
    __syncthreads();

    // ---- phase A: coalesced scan for this user's group members
    for (int j = t; j < N_ROWS; j += BLOCK) {
        if (user[j] == u) {
            const bool clicked = bytewise ? (click_u8[j] != 0)
                                          : (click_i32[j] != 0);
            int pos = atomicAdd(&cnt_lds, 1);
            if (pos < CAP) {
                mj[pos]   = j;
                mts[pos]  = ts[j];
                mclk[pos] = clicked ? 1 : 0;
            }
        }
    }
    __syncthreads();
    const int cnt = (cnt_lds < CAP) ? cnt_lds : CAP;

    // ---- phase B: rank sort by (ts, j). Total order -> deterministic.
    for (int p = t; p < cnt; p += BLOCK) {
        const float tp = mts[p];
        const int   jp = mj[p];
        int r = 0;
        for (int q = 0; q < cnt; ++q) {
            const float tq = mts[q];
            r += (tq < tp || (tq == tp && mj[q] < jp)) ? 1 : 0;
        }
        sj[r]   = jp;
        sts[r]  = tp;
        sclk[r] = mclk[p];
    }
    __syncthreads();

    // ---- phase C: serial walk in ts order. Thread t owns cols [2t,2t+1].
    const float2* __restrict__ emb2 = (const float2*)emb;
    float2* __restrict__ out2 = (float2*)out;
    constexpr int D2 = D_DIM / 2;  // 256

    float2 S = make_float2(0.f, 0.f);
    int c = 0;          // #clicked accumulated into S
    int run_start = 0;  // start of current equal-ts run

    for (int p = 0; p < cnt; ++p) {
        if (p > 0 && sts[p] != sts[p - 1]) {
            // flush clicked members of the completed tie-run
            for (int q = run_start; q < p; ++q) {
                if (sclk[q]) {
                    const float2 e = emb2[(size_t)sj[q] * D2 + t];
                    S.x += e.x;
                    S.y += e.y;
                    ++c;
                }
            }
            run_start = p;
        }
        const float inv = 1.0f / ((float)c + 1e-16f);
        out2[(size_t)sj[p] * D2 + t] = make_float2(S.x * inv, S.y * inv);
    }
}

// ---------------------------------------------------------------------------
extern "C" void kernel_launch(void* const* d_in, const int* in_sizes, int n_in,
                              void* d_out, int out_size, void* d_ws, size_t ws_size,
                              hipStream_t stream) {
    const int* user = (const int*)d_in[0];
    const float* ts = (const float*)d_in[1];
    const unsigned char* clicks = (const unsigned char*)d_in[2];
    const float* emb = (const float*)d_in[3];
    float* out = (float*)d_out;
    int* flag = (int*)d_ws;

    const int n = in_sizes[0];  // 8192
    (void)n_in; (void)out_size; (void)ws_size;

    uht_detect_bool_layout<<<1, BLOCK, 0, stream>>>(clicks, n, flag);
    uht_user_walk_kernel<8192, 512><<<N_USERS, BLOCK, 0, stream>>>(
        user, ts, clicks, emb, out, flag);
}

// Round 3
// 34.865 us; speedup vs baseline: 7.1712x; 1.0384x over previous
//
#include <hip/hip_runtime.h>

// out[i,:] = (1/(m_i + 1e-16)) * sum_j emb[j,:]  over
// S_i = { j : is_click[j] && user[j]==user[i] && ts[j] < ts[i] }
// N=8192, D=512, user in [0,256).
//
// Single fused kernel, one block per user:
//   A. vectorized load of user/ts/clicks (8x int4/float4/uchar4 per thread,
//      all independent -> one latency round trip) + inline is_click layout
//      detection + LDS-atomic compaction of this user's group.
//   B. rank sort by (ts, j) -- total order -> deterministic; compute
//      cbefore[p] = #{clicked q : ts[q] < ts[p]} (strict) directly.
//   C. stage clicked rows (sorted by ts) into LDS with independent pipelined
//      loads, then serial prefix walk over LDS writing out[row] = S/(c+eps).

constexpr int BLOCK   = 256;
constexpr int N_USERS = 256;
constexpr int CAP     = 192;  // max group members (mean 32, ~28 sigma margin)
constexpr int ECAP    = 48;   // clicked rows staged in LDS (mean 16, max ~30)

template <int N_ROWS, int D_DIM>
__global__ __launch_bounds__(BLOCK)
void uht_fused_kernel(const int* __restrict__ user,
                      const float* __restrict__ ts,
                      const unsigned char* __restrict__ click_u8,
                      const float* __restrict__ emb,
                      float* __restrict__ out) {
    constexpr int D2 = D_DIM / 2;            // 256 float2 per emb row
    constexpr int G  = N_ROWS / (BLOCK * 4); // 8 vec4 groups per thread
    const int u = blockIdx.x;
    const int t = threadIdx.x;

    extern __shared__ unsigned char smem[];
    float2* elds = (float2*)smem;                          // ECAP * D2 float2
    int*    mj   = (int*)(smem + (size_t)ECAP * D2 * sizeof(float2));
    float*  mts  = (float*)(mj + CAP);
    int*    mclk = (int*)(mts + CAP);
    int*    sj   = (int*)(mclk + CAP);
    float*  sts  = (float*)(sj + CAP);
    int*    sclk = (int*)(sts + CAP);
    int*    cbef = (int*)(sclk + CAP);
    int*    cljr = (int*)(cbef + CAP);   // emb row index per sorted click rank
    int*    misc = (int*)(cljr + CAP);   // [0]=cnt [1]=bytewise-flag [2]=nc

    if (t == 0) { misc[0] = 0; misc[1] = 0; misc[2] = 0; }
    __syncthreads();

    // ---- phase A: vectorized loads (independent -> pipelined)
    const int4*   u4 = (const int4*)user;
    const float4* t4 = (const float4*)ts;
    const uchar4* c4 = (const uchar4*)click_u8;

    int4 U[G]; float4 T[G]; uchar4 C[G];
    bool nz = false;
    #pragma unroll
    for (int k = 0; k < G; ++k) {
        const int idx = t + k * BLOCK;
        U[k] = u4[idx];
        T[k] = t4[idx];
        C[k] = c4[idx];  // bytes for rows 4*idx .. 4*idx+3
        nz = nz || (((int)C[k].y | (int)C[k].z | (int)C[k].w) != 0);
    }
    // layout detection: int32 bools have zero high bytes in every word;
    // byte-bools (~50% ones) have nonzero bytes at offsets %4 != 0.
    // All-false degenerate input -> int32 path, which reads zeros: correct.
    if (nz) atomicOr(&misc[1], 1);
    __syncthreads();
    const bool bytewise = (misc[1] != 0);

    int4 CI[G];
    if (!bytewise) {
        const int4* ci4 = (const int4*)click_u8;
        #pragma unroll
        for (int k = 0; k < G; ++k) CI[k] = ci4[t + k * BLOCK];
    }

    // ---- compaction (order-independent; sorted later)
    #pragma unroll
    for (int k = 0; k < G; ++k) {
        const int base = 4 * (t + k * BLOCK);
        const int   uu[4] = {U[k].x, U[k].y, U[k].z, U[k].w};
        const float tt[4] = {T[k].x, T[k].y, T[k].z, T[k].w};
        int cc[4];
        if (bytewise) { cc[0] = C[k].x;  cc[1] = C[k].y;  cc[2] = C[k].z;  cc[3] = C[k].w; }
        else          { cc[0] = CI[k].x; cc[1] = CI[k].y; cc[2] = CI[k].z; cc[3] = CI[k].w; }
        #pragma unroll
        for (int r = 0; r < 4; ++r) {
            if (uu[r] == u) {
                const int pos = atomicAdd(&misc[0], 1);
                if (pos < CAP) {
                    mj[pos]   = base + r;
                    mts[pos]  = tt[r];
                    mclk[pos] = (cc[r] != 0) ? 1 : 0;
                }
            }
        }
    }
    __syncthreads();
    const int cnt = min(misc[0], CAP);

    // ---- phase B: rank sort by (ts, j); CAP < BLOCK so one p per thread
    if (t < cnt) {
        const float tp = mts[t];
        const int   jp = mj[t];
        int r = 0;
        for (int q = 0; q < cnt; ++q) {
            const float tq = mts[q];
            r += (tq < tp || (tq == tp && mj[q] < jp)) ? 1 : 0;
        }
        sj[r] = jp; sts[r] = tp; sclk[r] = mclk[t];
    }
    __syncthreads();

    // counts: cbef[p] (strict-< clicked-before count), click ranks, nc
    if (t < cnt) {
        const float tp = sts[t];
        int cb = 0, pos = 0;
        for (int q = 0; q < cnt; ++q) {
            const int cq = sclk[q];
            cb  += (cq && (sts[q] < tp)) ? 1 : 0;
            pos += (cq && (q < t)) ? 1 : 0;
        }
        cbef[t] = cb;
        if (sclk[t]) cljr[pos] = sj[t];
        if (t == cnt - 1) misc[2] = pos + (sclk[t] ? 1 : 0);
    }
    __syncthreads();
    const int nc  = misc[2];
    const int ncs = min(nc, ECAP);

    // ---- phase C1: stage clicked rows into LDS (independent iterations)
    const float2* __restrict__ emb2 = (const float2*)emb;
    #pragma unroll 4
    for (int m = 0; m < ncs; ++m) {
        elds[m * D2 + t] = emb2[(size_t)cljr[m] * D2 + t];
    }
    __syncthreads();

    // ---- phase C2: serial prefix walk (thread t owns cols [2t, 2t+1]).
    // cbef is non-decreasing in sorted rank -> interleaved write-out valid.
    float2* __restrict__ out2 = (float2*)out;
    float2 acc = make_float2(0.f, 0.f);
    int p = 0;
    for (int k = 0; ; ++k) {
        const float inv = 1.0f / ((float)k + 1e-16f);
        while (p < cnt && cbef[p] == k) {
            out2[(size_t)sj[p] * D2 + t] = make_float2(acc.x * inv, acc.y * inv);
            ++p;
        }
        if (k >= nc) break;
        float2 e;
        if (k < ECAP) e = elds[k * D2 + t];
        else          e = emb2[(size_t)cljr[k] * D2 + t];  // overflow fallback
        acc.x += e.x;
        acc.y += e.y;
    }
}

// ---------------------------------------------------------------------------
extern "C" void kernel_launch(void* const* d_in, const int* in_sizes, int n_in,
                              void* d_out, int out_size, void* d_ws, size_t ws_size,
                              hipStream_t stream) {
    const int* user = (const int*)d_in[0];
    const float* ts = (const float*)d_in[1];
    const unsigned char* clicks = (const unsigned char*)d_in[2];
    const float* emb = (const float*)d_in[3];
    float* out = (float*)d_out;
    (void)in_sizes; (void)n_in; (void)out_size; (void)d_ws; (void)ws_size;

    constexpr int D2 = 512 / 2;
    const size_t shmem = (size_t)ECAP * D2 * sizeof(float2)  // 96 KiB staged emb
                       + (size_t)8 * CAP * sizeof(int)       // member/sort arrays
                       + 16;                                 // misc
    uht_fused_kernel<8192, 512><<<N_USERS, BLOCK, shmem, stream>>>(
        user, ts, clicks, emb, out);
}